// Round 1
// baseline (1524.770 us; speedup 1.0000x reference)
//
#include <hip/hip_runtime.h>
#include <hip/hip_fp16.h>

// GNN_6253472383532: dynamic top-k GCN block + BN + relu residual.
// b=16384, n=12, c=512, K(neighbors)=4.
//
// Math rewrite: agg = A @ (x@Vw^T + Vb) = (A@x)@Vw^T + rowsum(A) (x) Vb
// so h = [x|y] @ [Uw|Vw]^T + rs*Vb + Ub  with y = A@x  -> single K=1024 GEMM.

typedef _Float16 half8 __attribute__((ext_vector_type(8)));
typedef float floatx4 __attribute__((ext_vector_type(4)));

#define NN 12
#define CH 512
#define NB 16384
#define M_ROWS (NB * NN)  // 196608

__device__ __forceinline__ float relu_f(float v) { return v > 0.f ? v : 0.f; }

// ---------------------------------------------------------------------------
// Kw: build concatenated fp16 weights Wcat[d][k], k<512 -> Uw[d][k], else Vw.
// Also zero the BN global accumulators (24 doubles).
// ---------------------------------------------------------------------------
__global__ __launch_bounds__(256) void kw_build(const float* __restrict__ Uw,
                                                const float* __restrict__ Vw,
                                                _Float16* __restrict__ Wcat,
                                                double* __restrict__ gAcc) {
    int e = blockIdx.x * 256 + threadIdx.x;  // 0 .. 524287
    int d = e >> 10, k = e & 1023;
    float v = (k < 512) ? Uw[d * 512 + k] : Vw[d * 512 + (k - 512)];
    Wcat[e] = (_Float16)v;
    if (blockIdx.x == 0 && threadIdx.x < 24) gAcc[threadIdx.x] = 0.0;
}

// ---------------------------------------------------------------------------
// K1: per-batch adjacency (exact double sim -> top-4 threshold -> normalized
// A), y = A@x, rs = rowsum(A). Writes x and y as fp16 (pathA: [row][1024]
// concat; pathB: y only [row][512]).
// ---------------------------------------------------------------------------
__global__ __launch_bounds__(256) void k1_adj(const float* __restrict__ x,
                                              _Float16* __restrict__ Abuf,
                                              float* __restrict__ rs,
                                              int pathA) {
    __shared__ float xs[NN][CH + 1];   // +1 pad: conflict-free column reads
    __shared__ double sim[NN][NN];
    __shared__ double thr[NN];
    __shared__ float Amat[NN][NN];
    __shared__ float dinv[NN];

    const int b = blockIdx.x, t = threadIdx.x;
    const float* xb = x + (size_t)b * NN * CH;

    for (int e = t; e < NN * CH / 4; e += 256) {  // 1536 float4
        int r = e >> 7, c4 = (e & 127) << 2;
        float4 v = ((const float4*)xb)[e];
        xs[r][c4 + 0] = v.x; xs[r][c4 + 1] = v.y;
        xs[r][c4 + 2] = v.z; xs[r][c4 + 3] = v.w;
    }
    __syncthreads();

    if (t < 144) {  // 144 dot products, length 512, exact-product f64 accum
        int i = t / 12, j = t % 12;
        double acc = 0.0;
        for (int c = 0; c < CH; c++) acc += (double)xs[i][c] * (double)xs[j][c];
        sim[i][j] = acc;
    }
    __syncthreads();

    if (t < 12) {  // 4th largest (with duplicates) via top-4 insertion
        double a = -1e300, b2 = -1e300, c2 = -1e300, d2 = -1e300;
        for (int j = 0; j < 12; j++) {
            double v = sim[t][j];
            if (v > a)       { d2 = c2; c2 = b2; b2 = a; a = v; }
            else if (v > b2) { d2 = c2; c2 = b2; b2 = v; }
            else if (v > c2) { d2 = c2; c2 = v; }
            else if (v > d2) { d2 = v; }
        }
        thr[t] = d2;
        int deg = 0;
        for (int j = 0; j < 12; j++) deg += (sim[t][j] >= d2);
        dinv[t] = 1.0f / sqrtf((float)deg);
    }
    __syncthreads();

    if (t < 144) {
        int i = t / 12, j = t % 12;
        Amat[i][j] = (sim[i][j] >= thr[i]) ? dinv[i] * dinv[j] : 0.0f;
    }
    __syncthreads();

    if (t < 12) {
        float s = 0.f;
        for (int j = 0; j < 12; j++) s += Amat[t][j];
        rs[b * NN + t] = s;
    }

    const size_t strideK = pathA ? 1024 : 512;
    const size_t yoff = pathA ? 512 : 0;
    for (int e = t; e < NN * CH; e += 256) {
        int i = e >> 9, c = e & 511;
        float acc = 0.f;
#pragma unroll
        for (int j = 0; j < 12; j++) acc += Amat[i][j] * xs[j][c];
        size_t row = (size_t)b * NN + i;
        Abuf[row * strideK + yoff + c] = (_Float16)acc;
        if (pathA) Abuf[row * strideK + c] = (_Float16)xs[i][c];
    }
}

// ---------------------------------------------------------------------------
// K2: h = Acat @ Wcat^T + rs*Vb + Ub, written fp32 to d_out; fused BN partial
// sums (per n=m%12) -> global double atomics.
// Tile: BM=128 BN=128 BK=32, 4 waves, each 64x64 via 4x4 mfma 16x16x32 f16.
// ---------------------------------------------------------------------------
__global__ __launch_bounds__(256) void k2_gemm(
    const _Float16* __restrict__ Abuf, const float* __restrict__ xf,
    const _Float16* __restrict__ Wcat, const float* __restrict__ rs,
    const float* __restrict__ Ub, const float* __restrict__ Vb,
    float* __restrict__ hout, double* __restrict__ gS1,
    double* __restrict__ gS2, int pathA) {
    __shared__ __align__(16) _Float16 As[128 * 32];
    __shared__ __align__(16) _Float16 Bs[128 * 32];
    __shared__ float bs1[12], bs2[12];

    const int t = threadIdx.x;
    const int mt = blockIdx.x >> 2, nt = blockIdx.x & 3;
    const int m0 = mt * 128, n0 = nt * 128;
    const int lane = t & 63, wv = t >> 6;
    const int l15 = lane & 15, quad = lane >> 4;
    const int mwb = (wv & 1) * 64, nwb = (wv >> 1) * 64;
    const int srow = t >> 2, scol = (t & 3) * 8;  // staging: 8 elems/thread/pass

    floatx4 acc[4][4];
#pragma unroll
    for (int mi = 0; mi < 4; mi++)
#pragma unroll
        for (int ni = 0; ni < 4; ni++)
#pragma unroll
            for (int e = 0; e < 4; e++) acc[mi][ni][e] = 0.f;

    for (int kt = 0; kt < 32; kt++) {
        const int k0 = kt * 32;
        __syncthreads();
#pragma unroll
        for (int pass = 0; pass < 2; pass++) {
            const int row = srow + pass * 64;
            const size_t grow = (size_t)(m0 + row);
            half8 va;
            if (pathA) {
                va = *(const half8*)(Abuf + grow * 1024 + k0 + scol);
            } else if (k0 < 512) {
                const float* p = xf + grow * 512 + k0 + scol;
                float4 f0 = *(const float4*)p;
                float4 f1 = *(const float4*)(p + 4);
                va[0] = (_Float16)f0.x; va[1] = (_Float16)f0.y;
                va[2] = (_Float16)f0.z; va[3] = (_Float16)f0.w;
                va[4] = (_Float16)f1.x; va[5] = (_Float16)f1.y;
                va[6] = (_Float16)f1.z; va[7] = (_Float16)f1.w;
            } else {
                va = *(const half8*)(Abuf + grow * 512 + (k0 - 512) + scol);
            }
            *(half8*)&As[row * 32 + scol] = va;
            half8 vb = *(const half8*)(Wcat + (size_t)(n0 + row) * 1024 + k0 + scol);
            *(half8*)&Bs[row * 32 + scol] = vb;
        }
        __syncthreads();

        half8 af[4], bfr[4];
#pragma unroll
        for (int mi = 0; mi < 4; mi++)
            af[mi] = *(half8*)&As[(mwb + mi * 16 + l15) * 32 + quad * 8];
#pragma unroll
        for (int ni = 0; ni < 4; ni++)
            bfr[ni] = *(half8*)&Bs[(nwb + ni * 16 + l15) * 32 + quad * 8];
#pragma unroll
        for (int mi = 0; mi < 4; mi++)
#pragma unroll
            for (int ni = 0; ni < 4; ni++)
                acc[mi][ni] = __builtin_amdgcn_mfma_f32_16x16x32_f16(
                    af[mi], bfr[ni], acc[mi][ni], 0, 0, 0);
    }

    // epilogue: bias, store h, BN partials
    if (t < 12) { bs1[t] = 0.f; bs2[t] = 0.f; }
    __syncthreads();
#pragma unroll
    for (int mi = 0; mi < 4; mi++) {
#pragma unroll
        for (int r = 0; r < 4; r++) {
            const int m = m0 + mwb + mi * 16 + quad * 4 + r;
            const float rsm = rs[m];
            float p1 = 0.f, p2 = 0.f;
#pragma unroll
            for (int ni = 0; ni < 4; ni++) {
                const int d = n0 + nwb + ni * 16 + l15;
                float h = acc[mi][ni][r] + rsm * Vb[d] + Ub[d];
                hout[(size_t)m * 512 + d] = h;
                p1 += h; p2 += h * h;
            }
            // reduce across the 16 lanes holding row m (same quad group)
            for (int off = 1; off < 16; off <<= 1) {
                p1 += __shfl_xor(p1, off, 16);
                p2 += __shfl_xor(p2, off, 16);
            }
            if (l15 == 0) {
                atomicAdd(&bs1[m % 12], p1);
                atomicAdd(&bs2[m % 12], p2);
            }
        }
    }
    __syncthreads();
    if (t < 12) {
        atomicAdd(&gS1[t], (double)bs1[t]);
        atomicAdd(&gS2[t], (double)bs2[t]);
    }
}

// ---------------------------------------------------------------------------
// K3: finalize BN: scale[n] = gamma*rsqrt(var+eps), shift[n] = beta - mean*scale
// ---------------------------------------------------------------------------
__global__ void k3_stats(const double* __restrict__ gS1,
                         const double* __restrict__ gS2,
                         const float* __restrict__ gamma,
                         const float* __restrict__ beta,
                         float* __restrict__ bnp) {
    int t = threadIdx.x;
    if (t < 12) {
        const double cnt = (double)NB * 512.0;
        double mean = gS1[t] / cnt;
        double var = gS2[t] / cnt - mean * mean;
        float inv = rsqrtf((float)var + 1e-5f);
        float scale = gamma[t] * inv;
        bnp[t] = scale;
        bnp[12 + t] = beta[t] - (float)mean * scale;
    }
}

// ---------------------------------------------------------------------------
// K4: out = relu(x + h*scale[n] + shift[n]), in place over d_out (h).
// ---------------------------------------------------------------------------
__global__ __launch_bounds__(256) void k4_final(const float* __restrict__ x,
                                                float* __restrict__ out,
                                                const float* __restrict__ bnp) {
    __shared__ float sc[12], sh[12];
    if (threadIdx.x < 12) {
        sc[threadIdx.x] = bnp[threadIdx.x];
        sh[threadIdx.x] = bnp[12 + threadIdx.x];
    }
    __syncthreads();
    const size_t n4 = (size_t)M_ROWS * 128;  // float4 count
    for (size_t i = (size_t)blockIdx.x * 256 + threadIdx.x; i < n4;
         i += (size_t)gridDim.x * 256) {
        int m = (int)(i >> 7);
        int n = m % 12;
        float4 h = ((const float4*)out)[i];
        float4 xv = ((const float4*)x)[i];
        float s = sc[n], b = sh[n];
        float4 r;
        r.x = relu_f(xv.x + h.x * s + b);
        r.y = relu_f(xv.y + h.y * s + b);
        r.z = relu_f(xv.z + h.z * s + b);
        r.w = relu_f(xv.w + h.w * s + b);
        ((float4*)out)[i] = r;
    }
}

// ---------------------------------------------------------------------------
extern "C" void kernel_launch(void* const* d_in, const int* in_sizes, int n_in,
                              void* d_out, int out_size, void* d_ws,
                              size_t ws_size, hipStream_t stream) {
    const float* x     = (const float*)d_in[0];
    const float* Uw    = (const float*)d_in[1];
    const float* Ub    = (const float*)d_in[2];
    const float* Vw    = (const float*)d_in[3];
    const float* Vb    = (const float*)d_in[4];
    const float* gamma = (const float*)d_in[5];
    const float* beta  = (const float*)d_in[6];
    float* out = (float*)d_out;

    const size_t szA  = (size_t)M_ROWS * 1024 * 2;  // 402.7 MB fp16 [x|y]
    const size_t szB  = (size_t)M_ROWS * 512 * 2;   // 201.3 MB fp16 y only
    const size_t szW  = (size_t)512 * 1024 * 2;     // 1 MB
    const size_t szrs = (size_t)M_ROWS * 4;         // 0.79 MB
    const size_t needA = szA + szW + szrs + 24 * 8 + 24 * 4;
    const int pathA = (ws_size >= needA) ? 1 : 0;   // host-constant -> capture-safe

    char* w = (char*)d_ws;
    _Float16* Abuf = (_Float16*)w;
    const size_t big = pathA ? szA : szB;
    _Float16* Wcat = (_Float16*)(w + big);
    float* rs      = (float*)(w + big + szW);
    double* gS1    = (double*)(w + big + szW + szrs);
    double* gS2    = gS1 + 12;
    float* bnp     = (float*)(gS2 + 12);

    kw_build<<<2048, 256, 0, stream>>>(Uw, Vw, Wcat, gS1);
    k1_adj<<<NB, 256, 0, stream>>>(x, Abuf, rs, pathA);
    k2_gemm<<<(M_ROWS / 128) * 4, 256, 0, stream>>>(Abuf, x, Wcat, rs, Ub, Vb,
                                                    out, gS1, gS2, pathA);
    k3_stats<<<1, 64, 0, stream>>>(gS1, gS2, gamma, beta, bnp);
    k4_final<<<4096, 256, 0, stream>>>(x, out, bnp);
}